// Round 9
// baseline (480.556 us; speedup 1.0000x reference)
//
#include <hip/hip_runtime.h>

// B=16, Q=64, K=1024, H=256, Dv=256
#define LOG2E 1.4426950408889634f
#define TANH_SCALE 2.8853900817779268f   // 2*log2(e)
#define NEG_BIG -1e30f

typedef __attribute__((ext_vector_type(8))) short bf16x8;
typedef __attribute__((ext_vector_type(4))) float f32x4;
typedef _Float16 half4 __attribute__((ext_vector_type(4)));

static __device__ __forceinline__ short f2bf(float f) {
    unsigned u = __builtin_bit_cast(unsigned, f);
    u += 0x7fffu + ((u >> 16) & 1u);     // round-to-nearest-even
    return (short)(u >> 16);
}

// ---------------------------------------------------------------------------
// Projection via bf16 MFMA, direct-from-global fragments.
// queries -> eq[row][h] (row-major 1024x256).
// keys    -> ek4[g][global_key] float4, g = h>>2 (h-grouped transpose), written
//            COALESCED via an LDS-transposed epilogue (fixes the r7 scatter:
//            4B x 64 cache lines per store -> 512B contiguous runs).
// Block = 32M x 128N (4 waves, wave = 16M x 64N), grid 1088 blocks.
// ---------------------------------------------------------------------------
__global__ __launch_bounds__(256) void proj_mfma(const float* __restrict__ queries,
                                                 const float* __restrict__ keys,
                                                 const float* __restrict__ Wq,
                                                 const float* __restrict__ Wk,
                                                 float* __restrict__ eq,
                                                 float* __restrict__ ek4) {
    __shared__ float lds_t[128][33];     // [h_local][key_local], +1 pad

    const int mt = blockIdx.x >> 1, nt = blockIdx.x & 1;
    const int tid = threadIdx.x;
    const int w = tid >> 6, lane = tid & 63;
    const int wm = w >> 1, wn = w & 1;
    const int r = lane & 15, kq = lane >> 4;
    const int m0 = mt << 5;
    const int ncol = (nt << 7) + (wn << 6);

    const float* A; const float* W; int ar;
    if (m0 < 1024) { A = queries; W = Wq; ar = m0; }
    else           { A = keys;    W = Wk; ar = m0 - 1024; }

    const float* aptr = &A[(size_t)(ar + (wm << 4) + r) * 256];
    f32x4 acc[4] = {};

    #pragma unroll 2
    for (int ks = 0; ks < 8; ++ks) {
        const int k0 = (ks << 5) + (kq << 3);
        float4 fa0 = *reinterpret_cast<const float4*>(aptr + k0);
        float4 fa1 = *reinterpret_cast<const float4*>(aptr + k0 + 4);
        bf16x8 a = {f2bf(fa0.x), f2bf(fa0.y), f2bf(fa0.z), f2bf(fa0.w),
                    f2bf(fa1.x), f2bf(fa1.y), f2bf(fa1.z), f2bf(fa1.w)};
        #pragma unroll
        for (int nj = 0; nj < 4; ++nj) {
            const float* bp = &W[(size_t)(ncol + (nj << 4) + r) * 256 + k0];
            float4 fb0 = *reinterpret_cast<const float4*>(bp);
            float4 fb1 = *reinterpret_cast<const float4*>(bp + 4);
            bf16x8 bb = {f2bf(fb0.x), f2bf(fb0.y), f2bf(fb0.z), f2bf(fb0.w),
                         f2bf(fb1.x), f2bf(fb1.y), f2bf(fb1.z), f2bf(fb1.w)};
            acc[nj] = __builtin_amdgcn_mfma_f32_16x16x32_bf16(a, bb, acc[nj], 0, 0, 0);
        }
    }
    // C/D: col = lane&15 (r), row = kq*4 + t
    if (m0 < 1024) {
        #pragma unroll
        for (int nj = 0; nj < 4; ++nj)
            #pragma unroll
            for (int t = 0; t < 4; ++t) {
                int row = m0 + (wm << 4) + (kq << 2) + t;
                int col = ncol + (nj << 4) + r;
                eq[(size_t)row * 256 + col] =
                    __builtin_amdgcn_exp2f(TANH_SCALE * acc[nj][t]);
            }
    } else {
        #pragma unroll
        for (int nj = 0; nj < 4; ++nj)
            #pragma unroll
            for (int t = 0; t < 4; ++t) {
                int rloc = (wm << 4) + (kq << 2) + t;        // key_local 0..31
                int hloc = (wn << 6) + (nj << 4) + r;        // h_local   0..127
                lds_t[hloc][rloc] = __builtin_amdgcn_exp2f(TANH_SCALE * acc[nj][t]);
            }
        __syncthreads();
        const int g0 = nt << 5;
        const int R0 = m0 - 1024;
        float4* ek4f = reinterpret_cast<float4*>(ek4);
        #pragma unroll
        for (int it = 0; it < 4; ++it) {
            int idx = (it << 8) + tid;       // 0..1023
            int gl = idx >> 5, kk = idx & 31;
            float4 v = {lds_t[(gl << 2) + 0][kk], lds_t[(gl << 2) + 1][kk],
                        lds_t[(gl << 2) + 2][kk], lds_t[(gl << 2) + 3][kk]};
            ek4f[((size_t)(g0 + gl) << 14) + R0 + kk] = v;   // 512B runs, coalesced
        }
    }
}

// ---------------------------------------------------------------------------
// Fused attention: one 64-key chunk PER WAVE (no cross-wave load redundancy),
// 8 q per wave (32 rcp per ev load -> latency self-hiding), single-pass
// softmax per chunk (no online rescale), 16 fp16 partials per (b,q).
// Grid (qoct:8, b:16, seg:4); wave w -> chunk seg*4+w.
// ---------------------------------------------------------------------------
__global__ __launch_bounds__(256, 4) void attn_kernel(const float* __restrict__ eq,
                                                      const float* __restrict__ ek4,
                                                      const float* __restrict__ values,
                                                      const int* __restrict__ valid_lens,
                                                      const float* __restrict__ wv,
                                                      _Float16* __restrict__ part_acc,
                                                      float* __restrict__ part_m,
                                                      float* __restrict__ part_l) {
    __shared__ float4 q_lds[8 * 64];     // 8 q rows x 256 h: 8 KB
    __shared__ float4 wv_lds[64];        // 1 KB
    __shared__ float  p_lds[4][8][64];   // per-wave p: 8 KB

    const int tid = threadIdx.x;
    const int w = tid >> 6, lane = tid & 63;
    const int qoct = blockIdx.x, b = blockIdx.y, seg = blockIdx.z;
    const int q0 = qoct << 3;
    const int vl = valid_lens[b];
    const int cidx = (seg << 2) + w;     // 0..15, this wave's key chunk
    const int kstart = cidx << 6;

    // stage 8 q rows + wv once (block-wide)
    const float4* eqf = reinterpret_cast<const float4*>(eq);
    q_lds[tid]       = eqf[(size_t)((b << 6) + q0 + (tid >> 6)) * 64 + (tid & 63)];
    q_lds[tid + 256] = eqf[(size_t)((b << 6) + q0 + (tid >> 6) + 4) * 64 + (tid & 63)];
    if (tid < 64) wv_lds[tid] = reinterpret_cast<const float4*>(wv)[tid];
    __syncthreads();                     // ONLY barrier; early-out below is safe

    const int pbase = ((b << 6) + q0) << 4;     // + (qq<<4) + cidx

    if (kstart >= vl) {                  // inactive chunk: neutral partials
        half4 z = {};
        #pragma unroll
        for (int qq = 0; qq < 8; ++qq)
            *reinterpret_cast<half4*>(
                &part_acc[(size_t)(pbase + (qq << 4) + cidx) * 256 + (lane << 2)]) = z;
        if (lane < 8) {
            part_m[pbase + (lane << 4) + cidx] = NEG_BIG;
            part_l[pbase + (lane << 4) + cidx] = 0.f;
        }
        return;
    }

    // ---- scores: s[qq] over this wave's 64 keys (key = kstart + lane) ----
    float s[8] = {};
    const float4* ekc = reinterpret_cast<const float4*>(ek4) + ((b << 10) + kstart + lane);
    for (int hb = 0; hb < 8; ++hb) {
        float4 evr[8];
        #pragma unroll
        for (int i = 0; i < 8; ++i)
            evr[i] = ekc[(size_t)((hb << 3) + i) << 14];
        #pragma unroll
        for (int i = 0; i < 8; ++i) {
            const int h4 = (hb << 3) + i;
            const float4 wc = wv_lds[h4];
            #pragma unroll
            for (int qq = 0; qq < 8; ++qq) {
                const float4 qv = q_lds[(qq << 6) + h4];
                s[qq] += wc.x * __builtin_amdgcn_rcpf(fmaf(evr[i].x, qv.x, 1.0f))
                       + wc.y * __builtin_amdgcn_rcpf(fmaf(evr[i].y, qv.y, 1.0f))
                       + wc.z * __builtin_amdgcn_rcpf(fmaf(evr[i].z, qv.z, 1.0f))
                       + wc.w * __builtin_amdgcn_rcpf(fmaf(evr[i].w, qv.w, 1.0f));
            }
        }
    }

    // ---- single-pass softmax per q (chunk-local max/sum) ----
    const bool valid = (kstart + lane) < vl;
    #pragma unroll
    for (int qq = 0; qq < 8; ++qq) {
        float sc = valid ? (-2.0f * s[qq]) : NEG_BIG;
        float mx = sc;
        #pragma unroll
        for (int o = 32; o > 0; o >>= 1) mx = fmaxf(mx, __shfl_xor(mx, o));
        float p = __builtin_amdgcn_exp2f((sc - mx) * LOG2E);
        float ls = p;
        #pragma unroll
        for (int o = 32; o > 0; o >>= 1) ls += __shfl_xor(ls, o);
        p_lds[w][qq][lane] = p;
        if (lane == 0) {
            part_m[pbase + (qq << 4) + cidx] = mx;
            part_l[pbase + (qq << 4) + cidx] = ls;
        }
    }

    // ---- PV: invalid keys have p=0, so run all 64 unmasked ----
    f32x4 acc[8] = {};
    const float* vsrc = &values[(size_t)((b << 10) + kstart) * 256 + (lane << 2)];
    #pragma unroll 4
    for (int j = 0; j < 64; ++j) {
        float4 v = *reinterpret_cast<const float4*>(vsrc + j * 256);
        #pragma unroll
        for (int qq = 0; qq < 8; ++qq) {
            float p = p_lds[w][qq][j];
            acc[qq].x += p * v.x; acc[qq].y += p * v.y;
            acc[qq].z += p * v.z; acc[qq].w += p * v.w;
        }
    }

    #pragma unroll
    for (int qq = 0; qq < 8; ++qq) {
        half4 h = {(_Float16)acc[qq].x, (_Float16)acc[qq].y,
                   (_Float16)acc[qq].z, (_Float16)acc[qq].w};
        *reinterpret_cast<half4*>(
            &part_acc[(size_t)(pbase + (qq << 4) + cidx) * 256 + (lane << 2)]) = h;
    }
}

// ---------------------------------------------------------------------------
// Combine 16 chunk partials per (b,q). Grid 256 blocks; wave w -> q, lane -> 4 dv.
// ---------------------------------------------------------------------------
__global__ __launch_bounds__(256) void combine_kernel(const _Float16* __restrict__ part_acc,
                                                      const float* __restrict__ part_m,
                                                      const float* __restrict__ part_l,
                                                      float* __restrict__ out) {
    const int tid = threadIdx.x;
    const int w = tid >> 6, lane = tid & 63;
    const int b = blockIdx.x >> 4, qt = blockIdx.x & 15;
    const int q = (qt << 2) + w;
    const int base = ((b << 6) + q) << 4;

    float mm[16], ll[16];
    #pragma unroll
    for (int i = 0; i < 16; ++i) { mm[i] = part_m[base + i]; ll[i] = part_l[base + i]; }
    float M = mm[0];
    #pragma unroll
    for (int i = 1; i < 16; ++i) M = fmaxf(M, mm[i]);
    float wt[16];
    float L = 0.f;
    #pragma unroll
    for (int i = 0; i < 16; ++i) {
        wt[i] = __builtin_amdgcn_exp2f((mm[i] - M) * LOG2E);
        L += wt[i] * ll[i];
    }
    float invL = 1.0f / L;
    float4 o = {0.f, 0.f, 0.f, 0.f};
    #pragma unroll
    for (int i = 0; i < 16; ++i) {
        half4 v = *reinterpret_cast<const half4*>(
            &part_acc[(size_t)(base + i) * 256 + (lane << 2)]);
        o.x += wt[i] * (float)v.x; o.y += wt[i] * (float)v.y;
        o.z += wt[i] * (float)v.z; o.w += wt[i] * (float)v.w;
    }
    o.x *= invL; o.y *= invL; o.z *= invL; o.w *= invL;
    *reinterpret_cast<float4*>(&out[(size_t)((b << 6) + q) * 256 + (lane << 2)]) = o;
}

extern "C" void kernel_launch(void* const* d_in, const int* in_sizes, int n_in,
                              void* d_out, int out_size, void* d_ws, size_t ws_size,
                              hipStream_t stream) {
    const float* queries    = (const float*)d_in[0];  // [16,64,256]
    const float* keys       = (const float*)d_in[1];  // [16,1024,256]
    const float* values     = (const float*)d_in[2];  // [16,1024,256]
    const int*   valid_lens = (const int*)d_in[3];    // [16]
    const float* Wq         = (const float*)d_in[4];  // [256,256]
    const float* Wk         = (const float*)d_in[5];  // [256,256]
    const float* wv         = (const float*)d_in[6];  // [256]
    float* out = (float*)d_out;                       // [16,64,256]

    float*     eqw      = (float*)d_ws;                       // 1024*256 f32   (1 MB)
    float*     ek4      = eqw + 262144;                       // 64*16384 f4    (16 MB)
    _Float16*  part_acc = (_Float16*)(ek4 + 4194304);         // 16384*256 fp16 (8.4 MB)
    float*     part_m   = (float*)(part_acc + 4194304);       // 16384
    float*     part_l   = part_m + 16384;                     // 16384

    // projections: eq row-major; ek transposed+h-grouped (coalesced via LDS)
    proj_mfma<<<dim3(1088), 256, 0, stream>>>(queries, keys, Wq, Wk, eqw, ek4);
    // fused scores + chunk softmax + PV partials (1 chunk/wave, 8 q/wave)
    attn_kernel<<<dim3(8, 16, 4), 256, 0, stream>>>(eqw, ek4, values, valid_lens, wv,
                                                    part_acc, part_m, part_l);
    // merge 16 partials
    combine_kernel<<<dim3(256), 256, 0, stream>>>(part_acc, part_m, part_l, out);
}

// Round 10
// 176.725 us; speedup vs baseline: 2.7192x; 2.7192x over previous
//
#include <hip/hip_runtime.h>

// B=16, Q=64, K=1024, H=256, Dv=256
#define LOG2E 1.4426950408889634f
#define TANH_SCALE 2.8853900817779268f   // 2*log2(e)
#define NEG_BIG -1e30f

typedef __attribute__((ext_vector_type(8))) short bf16x8;
typedef __attribute__((ext_vector_type(4))) float f32x4;
typedef _Float16 half4 __attribute__((ext_vector_type(4)));

static __device__ __forceinline__ short f2bf(float f) {
    unsigned u = __builtin_bit_cast(unsigned, f);
    u += 0x7fffu + ((u >> 16) & 1u);     // round-to-nearest-even
    return (short)(u >> 16);
}

// ---------------------------------------------------------------------------
// Projection via bf16 MFMA, direct-from-global fragments.
// queries -> eq[row][h] (row-major 1024x256).
// keys    -> ek4[g][global_key] float4, g = h>>2, written coalesced via an
//            LDS-transposed epilogue (512B contiguous runs).
// Block = 32M x 128N (4 waves, wave = 16M x 64N), grid 1088 blocks.
// ---------------------------------------------------------------------------
__global__ __launch_bounds__(256) void proj_mfma(const float* __restrict__ queries,
                                                 const float* __restrict__ keys,
                                                 const float* __restrict__ Wq,
                                                 const float* __restrict__ Wk,
                                                 float* __restrict__ eq,
                                                 float* __restrict__ ek4) {
    __shared__ float lds_t[128][33];     // [h_local][key_local], +1 pad

    const int mt = blockIdx.x >> 1, nt = blockIdx.x & 1;
    const int tid = threadIdx.x;
    const int w = tid >> 6, lane = tid & 63;
    const int wm = w >> 1, wn = w & 1;
    const int r = lane & 15, kq = lane >> 4;
    const int m0 = mt << 5;
    const int ncol = (nt << 7) + (wn << 6);

    const float* A; const float* W; int ar;
    if (m0 < 1024) { A = queries; W = Wq; ar = m0; }
    else           { A = keys;    W = Wk; ar = m0 - 1024; }

    const float* aptr = &A[(size_t)(ar + (wm << 4) + r) * 256];
    f32x4 acc[4] = {};

    #pragma unroll 2
    for (int ks = 0; ks < 8; ++ks) {
        const int k0 = (ks << 5) + (kq << 3);
        float4 fa0 = *reinterpret_cast<const float4*>(aptr + k0);
        float4 fa1 = *reinterpret_cast<const float4*>(aptr + k0 + 4);
        bf16x8 a = {f2bf(fa0.x), f2bf(fa0.y), f2bf(fa0.z), f2bf(fa0.w),
                    f2bf(fa1.x), f2bf(fa1.y), f2bf(fa1.z), f2bf(fa1.w)};
        #pragma unroll
        for (int nj = 0; nj < 4; ++nj) {
            const float* bp = &W[(size_t)(ncol + (nj << 4) + r) * 256 + k0];
            float4 fb0 = *reinterpret_cast<const float4*>(bp);
            float4 fb1 = *reinterpret_cast<const float4*>(bp + 4);
            bf16x8 bb = {f2bf(fb0.x), f2bf(fb0.y), f2bf(fb0.z), f2bf(fb0.w),
                         f2bf(fb1.x), f2bf(fb1.y), f2bf(fb1.z), f2bf(fb1.w)};
            acc[nj] = __builtin_amdgcn_mfma_f32_16x16x32_bf16(a, bb, acc[nj], 0, 0, 0);
        }
    }
    // C/D: col = lane&15 (r), row = kq*4 + t
    if (m0 < 1024) {
        #pragma unroll
        for (int nj = 0; nj < 4; ++nj)
            #pragma unroll
            for (int t = 0; t < 4; ++t) {
                int row = m0 + (wm << 4) + (kq << 2) + t;
                int col = ncol + (nj << 4) + r;
                eq[(size_t)row * 256 + col] =
                    __builtin_amdgcn_exp2f(TANH_SCALE * acc[nj][t]);
            }
    } else {
        #pragma unroll
        for (int nj = 0; nj < 4; ++nj)
            #pragma unroll
            for (int t = 0; t < 4; ++t) {
                int rloc = (wm << 4) + (kq << 2) + t;        // key_local 0..31
                int hloc = (wn << 6) + (nj << 4) + r;        // h_local   0..127
                lds_t[hloc][rloc] = __builtin_amdgcn_exp2f(TANH_SCALE * acc[nj][t]);
            }
        __syncthreads();
        const int g0 = nt << 5;
        const int R0 = m0 - 1024;
        float4* ek4f = reinterpret_cast<float4*>(ek4);
        #pragma unroll
        for (int it = 0; it < 4; ++it) {
            int idx = (it << 8) + tid;       // 0..1023
            int gl = idx >> 5, kk = idx & 31;
            float4 v = {lds_t[(gl << 2) + 0][kk], lds_t[(gl << 2) + 1][kk],
                        lds_t[(gl << 2) + 2][kk], lds_t[(gl << 2) + 3][kk]};
            ek4f[((size_t)(g0 + gl) << 14) + R0 + kk] = v;   // 512B runs, coalesced
        }
    }
}

// ---------------------------------------------------------------------------
// Fused attention: one 64-key chunk per wave, 4 q per wave (acc fits VGPRs —
// r9's 8q spilled: 275MB scratch writes), single-pass chunk softmax,
// 16 fp16 partials per (b,q). NO __launch_bounds__ min-occupancy (r9 lesson:
// the bound capped VGPR at 64 and forced the spill).
// 1024 blocks, XCD-bijective swizzle: the 16 qquad-siblings of each (b,seg)
// (sharing ek+values chunks) land on one XCD.
// ---------------------------------------------------------------------------
__global__ __launch_bounds__(256) void attn_kernel(const float* __restrict__ eq,
                                                   const float* __restrict__ ek4,
                                                   const float* __restrict__ values,
                                                   const int* __restrict__ valid_lens,
                                                   const float* __restrict__ wv,
                                                   _Float16* __restrict__ part_acc,
                                                   float* __restrict__ part_m,
                                                   float* __restrict__ part_l) {
    __shared__ float4 q_lds[4 * 64];     // 4 q rows x 256 h: 4 KB
    __shared__ float4 wv_lds[64];        // 1 KB
    __shared__ float  p_lds[4][4][64];   // per-wave p: 4 KB

    const int tid = threadIdx.x;
    const int w = tid >> 6, lane = tid & 63;

    // bijective decode: 1024 = 8 xcd x 8 pp x 16 qquad; pair=(pp*8+xcd) -> (b,seg)
    const unsigned u = blockIdx.x;
    const int xcd = u & 7;
    const int i = u >> 3;                // 0..127
    const int qquad = i & 15;
    const int pp = i >> 4;               // 0..7
    const int pair = (pp << 3) + xcd;    // 0..63
    const int b = pair >> 2, seg = pair & 3;

    const int q0 = qquad << 2;
    const int vl = valid_lens[b];
    const int cidx = (seg << 2) + w;     // 0..15: this wave's key chunk
    const int kstart = cidx << 6;

    // stage 4 q rows + wv once (block-wide)
    const float4* eqf = reinterpret_cast<const float4*>(eq);
    q_lds[tid] = eqf[(size_t)((b << 6) + q0 + (tid >> 6)) * 64 + (tid & 63)];
    if (tid < 64) wv_lds[tid] = reinterpret_cast<const float4*>(wv)[tid];
    __syncthreads();                     // only barrier; early-out below is safe

    const int pbase = ((b << 6) + q0) << 4;     // + (qq<<4) + cidx

    if (kstart >= vl) {                  // inactive chunk: neutral partials
        half4 z = {};
        #pragma unroll
        for (int qq = 0; qq < 4; ++qq)
            *reinterpret_cast<half4*>(
                &part_acc[(size_t)(pbase + (qq << 4) + cidx) * 256 + (lane << 2)]) = z;
        if (lane < 4) {
            part_m[pbase + (lane << 4) + cidx] = NEG_BIG;
            part_l[pbase + (lane << 4) + cidx] = 0.f;
        }
        return;
    }

    // ---- scores: s[qq] over this wave's 64 keys (key = kstart + lane) ----
    float s0 = 0.f, s1 = 0.f, s2 = 0.f, s3 = 0.f;
    const float4* ekc = reinterpret_cast<const float4*>(ek4) + ((b << 10) + kstart + lane);
    #pragma unroll 4
    for (int h4 = 0; h4 < 64; ++h4) {
        float4 ev = ekc[(size_t)h4 << 14];       // coalesced, lane-consecutive
        float4 wc = wv_lds[h4];
        float4 q0v = q_lds[(0 << 6) + h4];
        float4 q1v = q_lds[(1 << 6) + h4];
        float4 q2v = q_lds[(2 << 6) + h4];
        float4 q3v = q_lds[(3 << 6) + h4];
        s0 += wc.x * __builtin_amdgcn_rcpf(fmaf(ev.x, q0v.x, 1.0f))
            + wc.y * __builtin_amdgcn_rcpf(fmaf(ev.y, q0v.y, 1.0f))
            + wc.z * __builtin_amdgcn_rcpf(fmaf(ev.z, q0v.z, 1.0f))
            + wc.w * __builtin_amdgcn_rcpf(fmaf(ev.w, q0v.w, 1.0f));
        s1 += wc.x * __builtin_amdgcn_rcpf(fmaf(ev.x, q1v.x, 1.0f))
            + wc.y * __builtin_amdgcn_rcpf(fmaf(ev.y, q1v.y, 1.0f))
            + wc.z * __builtin_amdgcn_rcpf(fmaf(ev.z, q1v.z, 1.0f))
            + wc.w * __builtin_amdgcn_rcpf(fmaf(ev.w, q1v.w, 1.0f));
        s2 += wc.x * __builtin_amdgcn_rcpf(fmaf(ev.x, q2v.x, 1.0f))
            + wc.y * __builtin_amdgcn_rcpf(fmaf(ev.y, q2v.y, 1.0f))
            + wc.z * __builtin_amdgcn_rcpf(fmaf(ev.z, q2v.z, 1.0f))
            + wc.w * __builtin_amdgcn_rcpf(fmaf(ev.w, q2v.w, 1.0f));
        s3 += wc.x * __builtin_amdgcn_rcpf(fmaf(ev.x, q3v.x, 1.0f))
            + wc.y * __builtin_amdgcn_rcpf(fmaf(ev.y, q3v.y, 1.0f))
            + wc.z * __builtin_amdgcn_rcpf(fmaf(ev.z, q3v.z, 1.0f))
            + wc.w * __builtin_amdgcn_rcpf(fmaf(ev.w, q3v.w, 1.0f));
    }

    // ---- single-pass softmax per q (chunk-local max/sum) ----
    const bool valid = (kstart + lane) < vl;
    float sarr[4] = {s0, s1, s2, s3};
    #pragma unroll
    for (int qq = 0; qq < 4; ++qq) {
        float sc = valid ? (-2.0f * sarr[qq]) : NEG_BIG;
        float mx = sc;
        #pragma unroll
        for (int o = 32; o > 0; o >>= 1) mx = fmaxf(mx, __shfl_xor(mx, o));
        float p = __builtin_amdgcn_exp2f((sc - mx) * LOG2E);
        float ls = p;
        #pragma unroll
        for (int o = 32; o > 0; o >>= 1) ls += __shfl_xor(ls, o);
        p_lds[w][qq][lane] = p;
        if (lane == 0) {
            part_m[pbase + (qq << 4) + cidx] = mx;
            part_l[pbase + (qq << 4) + cidx] = ls;
        }
    }

    // ---- PV: invalid keys have p=0, so run all 64 unmasked ----
    f32x4 a0 = {}, a1 = {}, a2 = {}, a3 = {};
    const float* vsrc = &values[(size_t)((b << 10) + kstart) * 256 + (lane << 2)];
    #pragma unroll 4
    for (int j = 0; j < 64; ++j) {
        float4 v = *reinterpret_cast<const float4*>(vsrc + j * 256);
        float p0 = p_lds[w][0][j], p1 = p_lds[w][1][j];
        float p2 = p_lds[w][2][j], p3 = p_lds[w][3][j];
        a0.x += p0 * v.x; a0.y += p0 * v.y; a0.z += p0 * v.z; a0.w += p0 * v.w;
        a1.x += p1 * v.x; a1.y += p1 * v.y; a1.z += p1 * v.z; a1.w += p1 * v.w;
        a2.x += p2 * v.x; a2.y += p2 * v.y; a2.z += p2 * v.z; a2.w += p2 * v.w;
        a3.x += p3 * v.x; a3.y += p3 * v.y; a3.z += p3 * v.z; a3.w += p3 * v.w;
    }

    f32x4 accs[4] = {a0, a1, a2, a3};
    #pragma unroll
    for (int qq = 0; qq < 4; ++qq) {
        half4 h = {(_Float16)accs[qq].x, (_Float16)accs[qq].y,
                   (_Float16)accs[qq].z, (_Float16)accs[qq].w};
        *reinterpret_cast<half4*>(
            &part_acc[(size_t)(pbase + (qq << 4) + cidx) * 256 + (lane << 2)]) = h;
    }
}

// ---------------------------------------------------------------------------
// Combine 16 chunk partials per (b,q). Grid 256 blocks; wave w -> q, lane -> 4 dv.
// ---------------------------------------------------------------------------
__global__ __launch_bounds__(256) void combine_kernel(const _Float16* __restrict__ part_acc,
                                                      const float* __restrict__ part_m,
                                                      const float* __restrict__ part_l,
                                                      float* __restrict__ out) {
    const int tid = threadIdx.x;
    const int w = tid >> 6, lane = tid & 63;
    const int b = blockIdx.x >> 4, qt = blockIdx.x & 15;
    const int q = (qt << 2) + w;
    const int base = ((b << 6) + q) << 4;

    float mm[16], ll[16];
    #pragma unroll
    for (int i = 0; i < 16; ++i) { mm[i] = part_m[base + i]; ll[i] = part_l[base + i]; }
    float M = mm[0];
    #pragma unroll
    for (int i = 1; i < 16; ++i) M = fmaxf(M, mm[i]);
    float wt[16];
    float L = 0.f;
    #pragma unroll
    for (int i = 0; i < 16; ++i) {
        wt[i] = __builtin_amdgcn_exp2f((mm[i] - M) * LOG2E);
        L += wt[i] * ll[i];
    }
    float invL = 1.0f / L;
    float4 o = {0.f, 0.f, 0.f, 0.f};
    #pragma unroll
    for (int i = 0; i < 16; ++i) {
        half4 v = *reinterpret_cast<const half4*>(
            &part_acc[(size_t)(base + i) * 256 + (lane << 2)]);
        o.x += wt[i] * (float)v.x; o.y += wt[i] * (float)v.y;
        o.z += wt[i] * (float)v.z; o.w += wt[i] * (float)v.w;
    }
    o.x *= invL; o.y *= invL; o.z *= invL; o.w *= invL;
    *reinterpret_cast<float4*>(&out[(size_t)((b << 6) + q) * 256 + (lane << 2)]) = o;
}

extern "C" void kernel_launch(void* const* d_in, const int* in_sizes, int n_in,
                              void* d_out, int out_size, void* d_ws, size_t ws_size,
                              hipStream_t stream) {
    const float* queries    = (const float*)d_in[0];  // [16,64,256]
    const float* keys       = (const float*)d_in[1];  // [16,1024,256]
    const float* values     = (const float*)d_in[2];  // [16,1024,256]
    const int*   valid_lens = (const int*)d_in[3];    // [16]
    const float* Wq         = (const float*)d_in[4];  // [256,256]
    const float* Wk         = (const float*)d_in[5];  // [256,256]
    const float* wv         = (const float*)d_in[6];  // [256]
    float* out = (float*)d_out;                       // [16,64,256]

    float*     eqw      = (float*)d_ws;                       // 1024*256 f32   (1 MB)
    float*     ek4      = eqw + 262144;                       // 64*16384 f4    (16 MB)
    _Float16*  part_acc = (_Float16*)(ek4 + 4194304);         // 16384*256 fp16 (8.4 MB)
    float*     part_m   = (float*)(part_acc + 4194304);       // 16384
    float*     part_l   = part_m + 16384;                     // 16384

    // projections: eq row-major; ek transposed+h-grouped (coalesced via LDS)
    proj_mfma<<<dim3(1088), 256, 0, stream>>>(queries, keys, Wq, Wk, eqw, ek4);
    // fused scores + chunk softmax + PV partials (1 chunk/wave, 4 q/wave)
    attn_kernel<<<dim3(1024), 256, 0, stream>>>(eqw, ek4, values, valid_lens, wv,
                                                part_acc, part_m, part_l);
    // merge 16 partials
    combine_kernel<<<dim3(256), 256, 0, stream>>>(part_acc, part_m, part_l, out);
}